// Round 1
// 61.465 us; speedup vs baseline: 1.0061x; 1.0061x over previous
//
#include <hip/hip_runtime.h>

// SConv2d with MAJ-gate tree (MAJ_DIM=3), N=8, C_IN=3, C_OUT=64, H=W=64, 3x3 conv s1 p1.
// maj3(a,b,c) = (a+b+c - abc)/2  (closed form of the combinatorial reference; verified R1).
// All three levels are maj3 over products:
//   L1 (kernel width j):  U = (w0x0 + w1x1 + w2x2) - (w0x0)(w1x1)(w2x2)   [= 2*m1]
//   L2 (kernel height i): m2 = 0.25*(Ua+Ub+Uc) - 0.0625*Ua*Ub*Uc          [0.5 of L1 folded in]
//   L3 (channels c):      m3 = 0.5*((a+b+d) - a*b*d)
//
// R2: grid 2048 blocks (channel-quartered), 4 channels/thread.
// R3: weights moved off the DS pipe. Previously 36 ds_read_b128/thread of wave-uniform
//     float4s (5x the x-tap LDS traffic) saturated the per-CU LDS pipe. Channel index is
//     wave-uniform -> readfirstlane forces s_load of raw weights through the scalar cache;
//     wl[] LDS buffer and the tid<144 staging branch are deleted. The 0.5 prescale is
//     absorbed algebraically into L2's constants, so no pre-scaled weight table is needed.

#define NC_OUT 64

__global__ __launch_bounds__(256, 6) void sconv_maj_kernel(
    const float* __restrict__ x,      // [8,3,64,64]
    const float* __restrict__ wgt,    // [64,3,3,3] -> flat [64,27]
    float* __restrict__ out)          // [8,64,64,64]
{
    __shared__ float xt[3 * 3 * 66];    // x tile: [c][i][col], col in [0,66)

    const int bid = blockIdx.x;
    const int q   = bid & 3;            // channel quarter: channels q*16 .. q*16+15
    const int h   = (bid >> 2) & 63;    // output row
    const int n   = bid >> 8;           // image index
    const int tid = threadIdx.x;

    // ---- stage x tile: rows h-1..h+1, cols -1..64, 3 channels (zero pad) ----
    for (int e = tid; e < 3 * 3 * 66; e += 256) {
        const int c   = e / 198;
        const int rem = e - c * 198;
        const int r   = rem / 66;
        const int col = rem - r * 66;
        const int gh  = h - 1 + r;
        const int gw  = col - 1;
        float v = 0.0f;
        if ((unsigned)gh < 64u && (unsigned)gw < 64u)
            v = x[((n * 3 + c) * 64 + gh) * 64 + gw];
        xt[e] = v;
    }
    __syncthreads();

    const int w  = tid & 63;                                  // output col (coalesced)
    const int su = __builtin_amdgcn_readfirstlane(tid >> 6);  // subgroup, forced SGPR

    // ---- per-position patch taps (channel-loop invariant) ----
    float xa[9], xb[9], xd[9];
    #pragma unroll
    for (int g = 0; g < 9; ++g) {
        xa[g] = xt[g * 66 + w + 0];
        xb[g] = xt[g * 66 + w + 1];
        xd[g] = xt[g * 66 + w + 2];
    }

    // ---- 4 output channels per thread; weights via uniform s_load ----
    const int co0 = q * 16 + su * 4;
    #pragma unroll
    for (int t = 0; t < 4; ++t) {
        const int co = co0 + t;                 // wave-uniform
        const float* wr = wgt + co * 27;        // -> s_load (scalar cache)
        float m2[3];
        #pragma unroll
        for (int c = 0; c < 3; ++c) {
            float U[3];
            #pragma unroll
            for (int i = 0; i < 3; ++i) {
                const int g = c * 3 + i;
                const float ap = wr[g * 3 + 0] * xa[g];   // v_mul, 1 sgpr operand each
                const float bp = wr[g * 3 + 1] * xb[g];
                const float dp = wr[g * 3 + 2] * xd[g];
                U[i] = (ap + bp + dp) - ap * bp * dp;     // 2*maj3(ap,bp,dp)
            }
            // maj3 of the three half-scaled L1 results, 0.5 folded into constants:
            m2[c] = fmaf(0.25f, U[0] + U[1] + U[2], -0.0625f * (U[0] * U[1] * U[2]));
        }
        const float a = m2[0], b = m2[1], d = m2[2];
        const float o = 0.5f * ((a + b + d) - a * b * d);
        out[((n * NC_OUT + co) * 64 + h) * 64 + w] = o;
    }
}

extern "C" void kernel_launch(void* const* d_in, const int* in_sizes, int n_in,
                              void* d_out, int out_size, void* d_ws, size_t ws_size,
                              hipStream_t stream) {
    const float* x   = (const float*)d_in[0];   // 8*3*64*64
    const float* wgt = (const float*)d_in[1];   // 64*3*3*3
    float* out = (float*)d_out;                 // 8*64*64*64
    // grid: (n, h, quarter): 8*64*4 = 2048 blocks
    sconv_maj_kernel<<<dim3(2048), dim3(256), 0, stream>>>(x, wgt, out);
}